// Round 9
// baseline (118.776 us; speedup 1.0000x reference)
//
#include <hip/hip_runtime.h>
#include <math.h>

// VectorQuantizer via MFMA: in [32,64,64,64] fp32 NCHW (C=D=64), w [512,64] fp32.
// R18 = R13 wave structure, 256 queries/block (each wave: 2 q-tiles x ALL codes).
// Amortizes per-block costs over 2x queries with zero added VALU per query:
//  - staging traffic + vmcnt drains per query halve (128KB wfrag serves 256 q)
//  - B ds_read volume per query halves (4x ds_read_b128 feeds 12 MFMAs not 6)
//  - barrier events per query halve; MFMA:ds_read ratio doubles
//  - grid 512 = 2 blocks/CU (16 waves/CU ~= the ~50% residency measured anyway)
// R16's T=2 failure was the code-split (duplicated A-prep + partial merge), not
// amortization -- here every wave scans all codes, no cross-half merge.
// VGPR guard: R16 measured this fragment count at 48 VGPR under (512,4); watch
// WRITE_SIZE == 32.8MB (spill tripwire, R15 lesson).
// Kept from R17: fmed3 sec-update (verified). Else verbatim R13 (47.2us best).
typedef short bf16x8 __attribute__((ext_vector_type(8)));
typedef float f32x4 __attribute__((ext_vector_type(4)));

#define VQ_D 64
#define VQ_K 512
#define VQ_NQ 131072
#define VQ_TOTAL 8388608
#define NCK 8            // staged chunks (4 tiles = 64 codes = 16 KB each)
#define QB 256           // queries per block
#define TAU 8e-3f

typedef __attribute__((address_space(1))) void as1_void;
typedef __attribute__((address_space(3))) void as3_void;

__device__ __forceinline__ void gll16(const void* g, void* l) {
    // global -> LDS direct copy, 16 B per lane; LDS dest = wave-uniform base + lane*16
    __builtin_amdgcn_global_load_lds((as1_void*)(void*)g, (as3_void*)l, 16, 0, 0);
}
__device__ __forceinline__ void gll4(const void* g, void* l) {
    __builtin_amdgcn_global_load_lds((as1_void*)(void*)g, (as3_void*)l, 4, 0, 0);
}

__device__ __forceinline__ ushort bf16_rne(float f) {
    uint u = __builtin_bit_cast(uint, f);
    u += 0x7fffu + ((u >> 16) & 1u);
    return (ushort)(u >> 16);
}
__device__ __forceinline__ float bf16_to_f(ushort h) {
    uint u = ((uint)h) << 16;
    return __builtin_bit_cast(float, u);
}
// bf16-RNE leaving the result in the TOP 16 bits (for v_perm packing)
__device__ __forceinline__ uint rne_top(float r) {
    uint t = __builtin_bit_cast(uint, r);
    return t + 0x7fffu + ((t >> 16) & 1u);
}
// pack top16(a) as low ushort, top16(b) as high ushort: one v_perm_b32
__device__ __forceinline__ uint pack_hi16(uint a, uint b) {
    return __builtin_amdgcn_perm(b, a, 0x07060302u);
}

// ---- prep: w -> bf16 hi/lo in MFMA B-fragment order + fp32 norms + loss=0 ----
// (verbatim R10/R11/R13: 8 threads per code, 32 blocks)
__global__ __launch_bounds__(128) void vq_prep(const float* __restrict__ w,
                                               ushort* __restrict__ wfrag,
                                               float* __restrict__ wn,
                                               float* __restrict__ out) {
    if (blockIdx.x == 0 && threadIdx.x == 0) out[VQ_TOTAL] = 0.f;
    const int tid = threadIdx.x;
    const int k = (blockIdx.x << 4) + (tid >> 3);   // code index
    const int g = tid & 7;                          // granule: d in [g*8, g*8+8)
    const float4* row = (const float4*)(w + k * VQ_D);
    float4 a = row[2 * g], b4 = row[2 * g + 1];
    float v[8] = {a.x, a.y, a.z, a.w, b4.x, b4.y, b4.z, b4.w};
    ushort hi[8], lo[8];
    float nrm = 0.f;
#pragma unroll
    for (int j = 0; j < 8; ++j) {
        nrm = fmaf(v[j], v[j], nrm);
        hi[j] = bf16_rne(v[j]);
        lo[j] = bf16_rne(v[j] - bf16_to_f(hi[j]));
    }
    // sum ||.||^2 over the code's 8 granules (lanes k*8..k*8+7, same wave)
    nrm += __shfl_xor(nrm, 1, 64);
    nrm += __shfl_xor(nrm, 2, 64);
    nrm += __shfl_xor(nrm, 4, 64);
    if (g == 0) wn[k] = nrm;
    const int t = k >> 4, col = k & 15;
    const int quad = g & 3, fh = g >> 2;
    bf16x8* basez = (bf16x8*)wfrag + t * 256 + quad * 16 + col;
    basez[fh * 64]       = *(bf16x8*)hi;    // bh{fh}
    basez[(2 + fh) * 64] = *(bf16x8*)lo;    // bl{fh}
}

__global__ __launch_bounds__(512, 4) void vq_main(const float* __restrict__ in,
                                                  const float* __restrict__ w,
                                                  const ushort* __restrict__ wfrag,
                                                  const float* __restrict__ wng,
                                                  float* __restrict__ out) {
    __shared__ __align__(16) char bstage[2][16384];  // double-buffered B chunks
    __shared__ float wn_lds[VQ_K];
    __shared__ float xn_lds[QB];
    __shared__ float best_lds[QB], sec_lds[QB];
    __shared__ int   bi_lds[QB], si_lds[QB];
    __shared__ double loss_lds[8];

    const int tid  = threadIdx.x;
    const int lane = tid & 63;
    const int wid  = tid >> 6;                 // 8 waves; wave owns 32 queries
    const int col  = lane & 15;
    const int quad = lane >> 4;
    const int n0  = blockIdx.x * QB;           // block's 256 queries (1/16 image)
    const int b   = n0 >> 12;
    const int hw0 = n0 & 4095;
    const float* xg0 = in + (b << 18) + hw0;

    // ---- prologue staging: chunk 0 (16 KB) + wn (2 KB); overlaps A-prep ----
    {
        const char* gs = (const char*)wfrag + tid * 16;     // per-lane global src
        char* lb = &bstage[0][0] + wid * 1024;              // wave-uniform LDS base
        gll16(gs, lb);
        gll16(gs + 8192, lb + 8192);
        gll4(wng + tid, (char*)wn_lds + wid * 256);         // 512 floats
    }

    // ---- A fragments direct from global (x, bf16 hi/lo) + xnorm ----
    // Wave owns 2 q-tiles: query = wid*32 + T*16 + col; A[m=col][k=quad*8+j].
    // (convert diet verbatim R13)
    bf16x8 ah0[2], ah1[2], al0[2], al1[2];
#pragma unroll
    for (int T = 0; T < 2; ++T) {
        const float* xq = xg0 + wid * 32 + T * 16 + col;
        float sx = 0.f;
        uint AH0[4], AL0[4], AH1[4], AL1[4];
#pragma unroll
        for (int m = 0; m < 4; ++m) {          // bf16 pair m: j = 2m, 2m+1
            float a0 = xq[(quad * 8 + 2 * m) << 12];          // kstep0: d in [0,32)
            float b0 = xq[(quad * 8 + 2 * m + 1) << 12];
            float a1 = xq[(32 + quad * 8 + 2 * m) << 12];     // kstep1: d in [32,64)
            float b1 = xq[(32 + quad * 8 + 2 * m + 1) << 12];
            sx = fmaf(a0, a0, sx); sx = fmaf(b0, b0, sx);
            sx = fmaf(a1, a1, sx); sx = fmaf(b1, b1, sx);
            uint ua0 = __builtin_bit_cast(uint, a0), ub0 = __builtin_bit_cast(uint, b0);
            uint ua1 = __builtin_bit_cast(uint, a1), ub1 = __builtin_bit_cast(uint, b1);
            AH0[m] = pack_hi16(ua0, ub0);
            AH1[m] = pack_hi16(ua1, ub1);
            float ha0 = __builtin_bit_cast(float, ua0 & 0xFFFF0000u);
            float hb0 = __builtin_bit_cast(float, ub0 & 0xFFFF0000u);
            float ha1 = __builtin_bit_cast(float, ua1 & 0xFFFF0000u);
            float hb1 = __builtin_bit_cast(float, ub1 & 0xFFFF0000u);
            AL0[m] = pack_hi16(rne_top(a0 - ha0), rne_top(b0 - hb0));
            AL1[m] = pack_hi16(rne_top(a1 - ha1), rne_top(b1 - hb1));
        }
        ah0[T] = *(bf16x8*)AH0; al0[T] = *(bf16x8*)AL0;
        ah1[T] = *(bf16x8*)AH1; al1[T] = *(bf16x8*)AL1;
        sx += __shfl_xor(sx, 16, 64);                   // sum the 4 quads
        sx += __shfl_xor(sx, 32, 64);
        if (quad == 0) xn_lds[wid * 32 + T * 16 + col] = sx;
    }

    __syncthreads();   // drains prologue gll (vmcnt) + xn_lds writes

    // ---- K-loop: B from LDS double buffer; each B-tile read feeds 2 q-tiles ----
    float best[2][4], sec[2][4];
#pragma unroll
    for (int T = 0; T < 2; ++T)
#pragma unroll
        for (int r = 0; r < 4; ++r) { best[T][r] = 3.0e38f; sec[T][r] = 3.0e38f; }

#pragma unroll 1
    for (int c = 0; c < NCK; ++c) {
        char* const bcur = &bstage[c & 1][0];
        if (c + 1 < NCK) {                      // prefetch next 16 KB chunk
            const char* gs = (const char*)wfrag + (c + 1) * 16384 + tid * 16;
            char* lb = &bstage[(c + 1) & 1][0] + wid * 1024;
            gll16(gs, lb);
            gll16(gs + 8192, lb + 8192);
        }
#pragma unroll
        for (int s = 0; s < 4; ++s) {           // four 16-code tiles per chunk
            const int t2 = 4 * c + s;
            const char* rb = bcur + s * 4096 + lane * 16;
            bf16x8 bh0 = *(const bf16x8*)(rb);
            bf16x8 bh1 = *(const bf16x8*)(rb + 1024);
            bf16x8 bl0 = *(const bf16x8*)(rb + 2048);
            bf16x8 bl1 = *(const bf16x8*)(rb + 3072);
            const float wnv = wn_lds[t2 * 16 + col];
#pragma unroll
            for (int T = 0; T < 2; ++T) {
                f32x4 acc = {0.f, 0.f, 0.f, 0.f};   // merged accumulator (R13)
                __builtin_amdgcn_s_setprio(1);
                acc = __builtin_amdgcn_mfma_f32_16x16x32_bf16(ah0[T], bh0, acc, 0, 0, 0);
                acc = __builtin_amdgcn_mfma_f32_16x16x32_bf16(ah1[T], bh1, acc, 0, 0, 0);
                acc = __builtin_amdgcn_mfma_f32_16x16x32_bf16(ah0[T], bl0, acc, 0, 0, 0);
                acc = __builtin_amdgcn_mfma_f32_16x16x32_bf16(ah1[T], bl1, acc, 0, 0, 0);
                acc = __builtin_amdgcn_mfma_f32_16x16x32_bf16(al0[T], bh0, acc, 0, 0, 0);
                acc = __builtin_amdgcn_mfma_f32_16x16x32_bf16(al1[T], bh1, acc, 0, 0, 0);
                __builtin_amdgcn_s_setprio(0);
#pragma unroll
                for (int j = 0; j < 4; ++j) {   // C: row(query)=quad*4+j, col=code
                    float dist = fmaf(-2.f, acc[j], wnv);
                    uint u = (__builtin_bit_cast(uint, dist) & 0xFFFFFFE0u)
                           | ((uint)t2 & 0x1Fu);    // fuses to v_bfi_b32
                    float key = __builtin_bit_cast(float, u);
                    // sec = median(best, sec, key) == fmax+fmin pair (R17, verified)
                    sec[T][j]  = __builtin_amdgcn_fmed3f(best[T][j], sec[T][j], key);
                    best[T][j] = fminf(best[T][j], key);
                }
            }
        }
        __syncthreads();   // chunk c reads done; chunk c+1 staged
    }

    // ---- unpack packed keys -> (dist_class, global code idx) ----
    float bD[2][4], sD[2][4];
    int bI[2][4], sI[2][4];
#pragma unroll
    for (int T = 0; T < 2; ++T)
#pragma unroll
    for (int r = 0; r < 4; ++r) {
        uint ub = __builtin_bit_cast(uint, best[T][r]);
        uint us = __builtin_bit_cast(uint, sec[T][r]);
        bI[T][r] = (int)(ub & 31u) * 16 + col;
        sI[T][r] = (int)(us & 31u) * 16 + col;
        bD[T][r] = __builtin_bit_cast(float, ub & 0xFFFFFFE0u);
        sD[T][r] = __builtin_bit_cast(float, us & 0xFFFFFFE0u);
    }

    // ---- merge across 16 col-lanes (comparator verbatim R13) ----
#pragma unroll
    for (int off = 1; off < 16; off <<= 1) {
#pragma unroll
        for (int T = 0; T < 2; ++T)
#pragma unroll
        for (int r = 0; r < 4; ++r) {
            float ob = __shfl_xor(bD[T][r], off, 64);
            float os = __shfl_xor(sD[T][r], off, 64);
            int   oi = __shfl_xor(bI[T][r], off, 64);
            int   oc = __shfl_xor(sI[T][r], off, 64);
            bool oWins = (ob < bD[T][r]) || (ob == bD[T][r] && oi < bI[T][r]);
            float nb  = oWins ? ob       : bD[T][r];
            int   ni  = oWins ? oi       : bI[T][r];
            float c1  = oWins ? bD[T][r] : ob;      // loser's best
            int   ci1 = oWins ? bI[T][r] : oi;
            float c2  = oWins ? os       : sD[T][r];   // winner's second
            int   ci2 = oWins ? oc       : sI[T][r];
            bool c1w = (c1 < c2) || (c1 == c2 && ci1 < ci2);
            sD[T][r] = c1w ? c1  : c2;
            sI[T][r] = c1w ? ci1 : ci2;
            bD[T][r] = nb; bI[T][r] = ni;
        }
    }
    if (col == 0) {
#pragma unroll
        for (int T = 0; T < 2; ++T)
#pragma unroll
        for (int r = 0; r < 4; ++r) {       // q in block = wid*32 + T*16 + quad*4 + r
            const int q = wid * 32 + T * 16 + quad * 4 + r;
            best_lds[q] = bD[T][r]; sec_lds[q] = sD[T][r];
            bi_lds[q] = bI[T][r];   si_lds[q] = sI[T][r];
        }
    }
    __syncthreads();

    // ---- epilogue: fp64 near-tie re-rank, 2 lanes per query + loss ----
    {
        const int q = tid >> 1, part = tid & 1;   // lanes 2k,2k+1 share query q
        float cb = best_lds[q], cs = sec_lds[q];
        int cbi = bi_lds[q], csi = si_lds[q];
        double chosen = (double)cb;
        if (cs - cb < TAU) {
            const float* wb  = w + cbi * VQ_D + part * 32;
            const float* ws2 = w + csi * VQ_D + part * 32;
            const float* xqp = xg0 + q;
            double nb = 0.0, dotb = 0.0, ns = 0.0, dots = 0.0;
#pragma unroll
            for (int d0 = 0; d0 < 32; ++d0) {
                const int d = part * 32 + d0;
                double xv = (double)xqp[d << 12];
                double wbv = (double)wb[d0], wsv = (double)ws2[d0];
                nb = fma(wbv, wbv, nb); dotb = fma(xv, wbv, dotb);
                ns = fma(wsv, wsv, ns); dots = fma(xv, wsv, dots);
            }
            // combine the 2 partials (pairwise butterfly)
            nb   += __shfl_xor(nb,   1, 64);
            dotb += __shfl_xor(dotb, 1, 64);
            ns   += __shfl_xor(ns,   1, 64);
            dots += __shfl_xor(dots, 1, 64);
            double db = nb - 2.0 * dotb, ds = ns - 2.0 * dots;
            if (ds < db || (ds == db && csi < cbi)) { cbi = csi; chosen = ds; }
            else                                    { chosen = db; }
        }
        if (part == 0) bi_lds[q] = cbi;
        double lq = (part == 0) ? ((double)xn_lds[q] + chosen) : 0.0;
#pragma unroll
        for (int off = 32; off > 0; off >>= 1)
            lq += __shfl_down(lq, off, 64);
        if (lane == 0) loss_lds[wid] = lq;
    }
    __syncthreads();
    if (tid == 0) {
        double s = 0.0;
#pragma unroll
        for (int wv = 0; wv < 8; ++wv) s += loss_lds[wv];
        atomicAdd(out + VQ_TOTAL, (float)(s * (1.0 / (double)VQ_TOTAL)));
    }

    // ---- cooperative quantized write: 2 threads/query ----
    {
        const int q = tid & 255, half = tid >> 8;  // half covers d in [32*half, +32)
        const float4* wrow = (const float4*)(w + bi_lds[q] * VQ_D) + half * 8;
        float* op = out + (b << 18) + hw0 + q;
#pragma unroll
        for (int u = 0; u < 8; ++u) {
            float4 v = wrow[u];
            const int d = half * 32 + 4 * u;
            op[(d + 0) << 12] = v.x;
            op[(d + 1) << 12] = v.y;
            op[(d + 2) << 12] = v.z;
            op[(d + 3) << 12] = v.w;
        }
    }
}

extern "C" void kernel_launch(void* const* d_in, const int* in_sizes, int n_in,
                              void* d_out, int out_size, void* d_ws, size_t ws_size,
                              hipStream_t stream) {
    const float* in = (const float*)d_in[0];
    const float* w  = (const float*)d_in[1];
    float* out = (float*)d_out;

    ushort* wfrag = (ushort*)d_ws;                    // 512*128 ushort = 128 KB
    float*  wn    = (float*)((char*)d_ws + 131072);   // 512 floats

    vq_prep<<<32, 128, 0, stream>>>(w, wfrag, wn, out);   // also zeroes loss cell
    vq_main<<<VQ_NQ / QB, 512, 0, stream>>>(in, w, wfrag, wn, out);
}

// Round 10
// 115.377 us; speedup vs baseline: 1.0295x; 1.0295x over previous
//
#include <hip/hip_runtime.h>
#include <math.h>

// VectorQuantizer via MFMA: in [32,64,64,64] fp32 NCHW (C=D=64), w [512,64] fp32.
// R19 = R13 (best: 47.2us kernel / 116.6us bench) + two deltas:
//  - fmed3 sec-update (from R17, verified 2x at absmax 1.2e-4): 1 VALU saved
//    per C-element.
//  - s_setprio REMOVED (first isolation since R10): our K-loop is the lockstep
//    regime where setprio measured null-to-negative (m190 GEMM -14TF); priority
//    boost around MFMA clusters can starve co-resident waves' staging issue.
// R18 lesson: halving LDS-read volume per query made things WORSE (53.3 vs
// 47.2) -> no single pipe is binding; block-level parallelism (4 independent
// barrier groups/CU) is worth more than any pipe-volume saving. Hence minimal
// diff on the best-known structure.
// Staging / A-prep / distance math / key packing / merge / fp64 re-rank /
// epilogues: verbatim R13 (passed, absmax 1.2e-4).
typedef short bf16x8 __attribute__((ext_vector_type(8)));
typedef float f32x4 __attribute__((ext_vector_type(4)));

#define VQ_D 64
#define VQ_K 512
#define VQ_NQ 131072
#define VQ_TOTAL 8388608
#define NCK 8            // staged chunks (4 tiles = 64 codes = 16 KB each)
#define TAU 8e-3f

typedef __attribute__((address_space(1))) void as1_void;
typedef __attribute__((address_space(3))) void as3_void;

__device__ __forceinline__ void gll16(const void* g, void* l) {
    // global -> LDS direct copy, 16 B per lane; LDS dest = wave-uniform base + lane*16
    __builtin_amdgcn_global_load_lds((as1_void*)(void*)g, (as3_void*)l, 16, 0, 0);
}
__device__ __forceinline__ void gll4(const void* g, void* l) {
    __builtin_amdgcn_global_load_lds((as1_void*)(void*)g, (as3_void*)l, 4, 0, 0);
}

__device__ __forceinline__ ushort bf16_rne(float f) {
    uint u = __builtin_bit_cast(uint, f);
    u += 0x7fffu + ((u >> 16) & 1u);
    return (ushort)(u >> 16);
}
__device__ __forceinline__ float bf16_to_f(ushort h) {
    uint u = ((uint)h) << 16;
    return __builtin_bit_cast(float, u);
}
// bf16-RNE leaving the result in the TOP 16 bits (for v_perm packing)
__device__ __forceinline__ uint rne_top(float r) {
    uint t = __builtin_bit_cast(uint, r);
    return t + 0x7fffu + ((t >> 16) & 1u);
}
// pack top16(a) as low ushort, top16(b) as high ushort: one v_perm_b32
__device__ __forceinline__ uint pack_hi16(uint a, uint b) {
    return __builtin_amdgcn_perm(b, a, 0x07060302u);
}

// ---- prep: w -> bf16 hi/lo in MFMA B-fragment order + fp32 norms + loss=0 ----
// (verbatim R10/R11/R13: 8 threads per code, 32 blocks)
__global__ __launch_bounds__(128) void vq_prep(const float* __restrict__ w,
                                               ushort* __restrict__ wfrag,
                                               float* __restrict__ wn,
                                               float* __restrict__ out) {
    if (blockIdx.x == 0 && threadIdx.x == 0) out[VQ_TOTAL] = 0.f;
    const int tid = threadIdx.x;
    const int k = (blockIdx.x << 4) + (tid >> 3);   // code index
    const int g = tid & 7;                          // granule: d in [g*8, g*8+8)
    const float4* row = (const float4*)(w + k * VQ_D);
    float4 a = row[2 * g], b4 = row[2 * g + 1];
    float v[8] = {a.x, a.y, a.z, a.w, b4.x, b4.y, b4.z, b4.w};
    ushort hi[8], lo[8];
    float nrm = 0.f;
#pragma unroll
    for (int j = 0; j < 8; ++j) {
        nrm = fmaf(v[j], v[j], nrm);
        hi[j] = bf16_rne(v[j]);
        lo[j] = bf16_rne(v[j] - bf16_to_f(hi[j]));
    }
    // sum ||.||^2 over the code's 8 granules (lanes k*8..k*8+7, same wave)
    nrm += __shfl_xor(nrm, 1, 64);
    nrm += __shfl_xor(nrm, 2, 64);
    nrm += __shfl_xor(nrm, 4, 64);
    if (g == 0) wn[k] = nrm;
    const int t = k >> 4, col = k & 15;
    const int quad = g & 3, fh = g >> 2;
    bf16x8* basez = (bf16x8*)wfrag + t * 256 + quad * 16 + col;
    basez[fh * 64]       = *(bf16x8*)hi;    // bh{fh}
    basez[(2 + fh) * 64] = *(bf16x8*)lo;    // bl{fh}
}

__global__ __launch_bounds__(512, 8) void vq_main(const float* __restrict__ in,
                                                  const float* __restrict__ w,
                                                  const ushort* __restrict__ wfrag,
                                                  const float* __restrict__ wng,
                                                  float* __restrict__ out) {
    __shared__ __align__(16) char bstage[2][16384];  // double-buffered B chunks
    __shared__ float wn_lds[VQ_K];
    __shared__ float xn_lds[128];
    __shared__ float best_lds[128], sec_lds[128];
    __shared__ int   bi_lds[128], si_lds[128];
    __shared__ double loss_lds[8];

    const int tid  = threadIdx.x;
    const int lane = tid & 63;
    const int wid  = tid >> 6;                 // 8 waves
    const int col  = lane & 15;
    const int quad = lane >> 4;
    const int n0  = blockIdx.x * 128;          // block's 128 queries (one image)
    const int b   = n0 >> 12;
    const int hw0 = n0 & 4095;
    const float* xg0 = in + (b << 18) + hw0;

    // ---- prologue staging: chunk 0 (16 KB) + wn (2 KB); overlaps A-prep ----
    {
        const char* gs = (const char*)wfrag + tid * 16;     // per-lane global src
        char* lb = &bstage[0][0] + wid * 1024;              // wave-uniform LDS base
        gll16(gs, lb);
        gll16(gs + 8192, lb + 8192);
        gll4(wng + tid, (char*)wn_lds + wid * 256);         // 512 floats
    }

    // ---- A fragments direct from global (x, bf16 hi/lo) + xnorm (R13 verbatim) ----
    // 16 queries per wave: query = wid*16 + col; A[m=col][k=quad*8+j].
    bf16x8 ah0, ah1, al0, al1;
    {
        const float* xq = xg0 + wid * 16 + col;
        float sx = 0.f;
        uint AH0[4], AL0[4], AH1[4], AL1[4];
#pragma unroll
        for (int m = 0; m < 4; ++m) {          // bf16 pair m: j = 2m, 2m+1
            float a0 = xq[(quad * 8 + 2 * m) << 12];          // kstep0: d in [0,32)
            float b0 = xq[(quad * 8 + 2 * m + 1) << 12];
            float a1 = xq[(32 + quad * 8 + 2 * m) << 12];     // kstep1: d in [32,64)
            float b1 = xq[(32 + quad * 8 + 2 * m + 1) << 12];
            sx = fmaf(a0, a0, sx); sx = fmaf(b0, b0, sx);
            sx = fmaf(a1, a1, sx); sx = fmaf(b1, b1, sx);
            uint ua0 = __builtin_bit_cast(uint, a0), ub0 = __builtin_bit_cast(uint, b0);
            uint ua1 = __builtin_bit_cast(uint, a1), ub1 = __builtin_bit_cast(uint, b1);
            AH0[m] = pack_hi16(ua0, ub0);
            AH1[m] = pack_hi16(ua1, ub1);
            float ha0 = __builtin_bit_cast(float, ua0 & 0xFFFF0000u);
            float hb0 = __builtin_bit_cast(float, ub0 & 0xFFFF0000u);
            float ha1 = __builtin_bit_cast(float, ua1 & 0xFFFF0000u);
            float hb1 = __builtin_bit_cast(float, ub1 & 0xFFFF0000u);
            AL0[m] = pack_hi16(rne_top(a0 - ha0), rne_top(b0 - hb0));
            AL1[m] = pack_hi16(rne_top(a1 - ha1), rne_top(b1 - hb1));
        }
        ah0 = *(bf16x8*)AH0; al0 = *(bf16x8*)AL0;
        ah1 = *(bf16x8*)AH1; al1 = *(bf16x8*)AL1;
        sx += __shfl_xor(sx, 16, 64);                   // sum the 4 quads
        sx += __shfl_xor(sx, 32, 64);
        if (quad == 0) xn_lds[wid * 16 + col] = sx;
    }

    __syncthreads();   // drains prologue gll (vmcnt) + xn_lds writes

    // ---- K-loop: B from LDS double buffer; dist = fmaf(-2, acc, wn) ----
    float best[4], sec[4];
#pragma unroll
    for (int r = 0; r < 4; ++r) { best[r] = 3.0e38f; sec[r] = 3.0e38f; }

#pragma unroll 1
    for (int c = 0; c < NCK; ++c) {
        char* const bcur = &bstage[c & 1][0];
        if (c + 1 < NCK) {                      // prefetch next 16 KB chunk
            const char* gs = (const char*)wfrag + (c + 1) * 16384 + tid * 16;
            char* lb = &bstage[(c + 1) & 1][0] + wid * 1024;
            gll16(gs, lb);
            gll16(gs + 8192, lb + 8192);
        }
#pragma unroll
        for (int s = 0; s < 4; ++s) {           // four 16-code tiles per chunk
            const int t2 = 4 * c + s;
            const char* rb = bcur + s * 4096 + lane * 16;
            bf16x8 bh0 = *(const bf16x8*)(rb);
            bf16x8 bh1 = *(const bf16x8*)(rb + 1024);
            bf16x8 bl0 = *(const bf16x8*)(rb + 2048);
            bf16x8 bl1 = *(const bf16x8*)(rb + 3072);
            const float wnv = wn_lds[t2 * 16 + col];
            f32x4 acc = {0.f, 0.f, 0.f, 0.f};   // merged accumulator (R13)
            acc = __builtin_amdgcn_mfma_f32_16x16x32_bf16(ah0, bh0, acc, 0, 0, 0);
            acc = __builtin_amdgcn_mfma_f32_16x16x32_bf16(ah1, bh1, acc, 0, 0, 0);
            acc = __builtin_amdgcn_mfma_f32_16x16x32_bf16(ah0, bl0, acc, 0, 0, 0);
            acc = __builtin_amdgcn_mfma_f32_16x16x32_bf16(ah1, bl1, acc, 0, 0, 0);
            acc = __builtin_amdgcn_mfma_f32_16x16x32_bf16(al0, bh0, acc, 0, 0, 0);
            acc = __builtin_amdgcn_mfma_f32_16x16x32_bf16(al1, bh1, acc, 0, 0, 0);
#pragma unroll
            for (int j = 0; j < 4; ++j) {       // C: row(query)=quad*4+j, col=code
                float dist = fmaf(-2.f, acc[j], wnv);
                uint u = (__builtin_bit_cast(uint, dist) & 0xFFFFFFE0u)
                       | ((uint)t2 & 0x1Fu);    // fuses to v_bfi_b32
                float key = __builtin_bit_cast(float, u);
                // sec = median(best, sec, key) == fmax+fmin pair (verified R17/R18)
                sec[j]  = __builtin_amdgcn_fmed3f(best[j], sec[j], key);
                best[j] = fminf(best[j], key);
            }
        }
        __syncthreads();   // chunk c reads done; chunk c+1 staged
    }

    // ---- unpack packed keys -> (dist_class, global code idx) (R13 verbatim) ----
    float bD[4], sD[4];
    int bI[4], sI[4];
#pragma unroll
    for (int r = 0; r < 4; ++r) {
        uint ub = __builtin_bit_cast(uint, best[r]);
        uint us = __builtin_bit_cast(uint, sec[r]);
        bI[r] = (int)(ub & 31u) * 16 + col;
        sI[r] = (int)(us & 31u) * 16 + col;
        bD[r] = __builtin_bit_cast(float, ub & 0xFFFFFFE0u);
        sD[r] = __builtin_bit_cast(float, us & 0xFFFFFFE0u);
    }

    // ---- merge across 16 col-lanes (R13 verbatim) ----
#pragma unroll
    for (int off = 1; off < 16; off <<= 1) {
#pragma unroll
        for (int r = 0; r < 4; ++r) {
            float ob = __shfl_xor(bD[r], off, 64);
            float os = __shfl_xor(sD[r], off, 64);
            int   oi = __shfl_xor(bI[r], off, 64);
            int   oc = __shfl_xor(sI[r], off, 64);
            bool oWins = (ob < bD[r]) || (ob == bD[r] && oi < bI[r]);
            float nb  = oWins ? ob    : bD[r];
            int   ni  = oWins ? oi    : bI[r];
            float c1  = oWins ? bD[r] : ob;      // loser's best
            int   ci1 = oWins ? bI[r] : oi;
            float c2  = oWins ? os    : sD[r];   // winner's second
            int   ci2 = oWins ? oc    : sI[r];
            bool c1w = (c1 < c2) || (c1 == c2 && ci1 < ci2);
            sD[r] = c1w ? c1  : c2;
            sI[r] = c1w ? ci1 : ci2;
            bD[r] = nb; bI[r] = ni;
        }
    }
    if (col == 0) {
#pragma unroll
        for (int r = 0; r < 4; ++r) {           // q in block = wid*16 + quad*4 + r
            const int q = wid * 16 + quad * 4 + r;
            best_lds[q] = bD[r]; sec_lds[q] = sD[r];
            bi_lds[q] = bI[r];   si_lds[q] = sI[r];
        }
    }
    __syncthreads();

    // ---- epilogue: fp64 near-tie re-rank, 4 lanes per query + loss (R13 verbatim) ----
    {
        const int q = tid >> 2, part = tid & 3;   // lanes 4k..4k+3 share query q
        float cb = best_lds[q], cs = sec_lds[q];
        int cbi = bi_lds[q], csi = si_lds[q];
        double chosen = (double)cb;
        if (cs - cb < TAU) {
            const float* wb  = w + cbi * VQ_D + part * 16;
            const float* ws2 = w + csi * VQ_D + part * 16;
            const float* xqp = xg0 + q;
            double nb = 0.0, dotb = 0.0, ns = 0.0, dots = 0.0;
#pragma unroll
            for (int d0 = 0; d0 < 16; ++d0) {
                const int d = part * 16 + d0;
                double xv = (double)xqp[d << 12];
                double wbv = (double)wb[d0], wsv = (double)ws2[d0];
                nb = fma(wbv, wbv, nb); dotb = fma(xv, wbv, dotb);
                ns = fma(wsv, wsv, ns); dots = fma(xv, wsv, dots);
            }
            // combine the 4 partials (butterfly within the 4-lane group)
#pragma unroll
            for (int off = 1; off < 4; off <<= 1) {
                nb   += __shfl_xor(nb,   off, 64);
                dotb += __shfl_xor(dotb, off, 64);
                ns   += __shfl_xor(ns,   off, 64);
                dots += __shfl_xor(dots, off, 64);
            }
            double db = nb - 2.0 * dotb, ds = ns - 2.0 * dots;
            if (ds < db || (ds == db && csi < cbi)) { cbi = csi; chosen = ds; }
            else                                    { chosen = db; }
        }
        if (part == 0) bi_lds[q] = cbi;
        double lq = (part == 0) ? ((double)xn_lds[q] + chosen) : 0.0;
#pragma unroll
        for (int off = 32; off > 0; off >>= 1)
            lq += __shfl_down(lq, off, 64);
        if (lane == 0) loss_lds[wid] = lq;
    }
    __syncthreads();
    if (tid == 0) {
        double s = 0.0;
#pragma unroll
        for (int wv = 0; wv < 8; ++wv) s += loss_lds[wv];
        atomicAdd(out + VQ_TOTAL, (float)(s * (1.0 / (double)VQ_TOTAL)));
    }

    // ---- cooperative quantized write: 4 threads/query (R13 verbatim) ----
    {
        const int q = tid & 127, quarter = tid >> 7;  // quarter: d in [16*quarter, +16)
        const float4* wrow = (const float4*)(w + bi_lds[q] * VQ_D) + quarter * 4;
        float* op = out + (b << 18) + hw0 + q;
#pragma unroll
        for (int u = 0; u < 4; ++u) {
            float4 v = wrow[u];
            const int d = quarter * 16 + 4 * u;
            op[(d + 0) << 12] = v.x;
            op[(d + 1) << 12] = v.y;
            op[(d + 2) << 12] = v.z;
            op[(d + 3) << 12] = v.w;
        }
    }
}

extern "C" void kernel_launch(void* const* d_in, const int* in_sizes, int n_in,
                              void* d_out, int out_size, void* d_ws, size_t ws_size,
                              hipStream_t stream) {
    const float* in = (const float*)d_in[0];
    const float* w  = (const float*)d_in[1];
    float* out = (float*)d_out;

    ushort* wfrag = (ushort*)d_ws;                    // 512*128 ushort = 128 KB
    float*  wn    = (float*)((char*)d_ws + 131072);   // 512 floats

    vq_prep<<<32, 128, 0, stream>>>(w, wfrag, wn, out);   // also zeroes loss cell
    vq_main<<<VQ_NQ / 128, 512, 0, stream>>>(in, w, wfrag, wn, out);
}